// Round 1
// baseline (139.924 us; speedup 1.0000x reference)
//
#include <hip/hip_runtime.h>

#define N 1024
#define NUM_IN 2048
#define NE (N * N)              // 1048576 elements of W_rec
#define TAU 20.0f
#define LR 0.001f

// ---------------- Stage 1a: partial sums of total_current -------------------
// 3072 logical reduction rows (2048 W_in + 1024 W_rec), split into 16 chunks
// of 192 rows. Grid 64 blocks: blockIdx = jg (4 column groups) x ic (16 chunks).
__global__ __launch_bounds__(256) void lif_partial(
    const float* __restrict__ in_spk, const float* __restrict__ prev_spk,
    const float* __restrict__ W_in, const float* __restrict__ W_rec,
    float* __restrict__ partial) {
    int jg = blockIdx.x & 3;
    int ic = blockIdx.x >> 2;
    int j = jg * 256 + threadIdx.x;
    float acc = 0.f;
    int r0 = ic * 192, r1 = r0 + 192;
    for (int r = r0; r < r1; ++r) {
        if (r < NUM_IN) {
            float s = in_spk[r];                 // broadcast load, wave-uniform
            if (s != 0.f) acc = fmaf(s, W_in[r * N + j], acc);
        } else {
            float s = prev_spk[r - NUM_IN];
            if (s != 0.f) acc = fmaf(s, W_rec[(r - NUM_IN) * N + j], acc);
        }
    }
    partial[ic * N + j] = acc;
}

// ---------------- Stage 1b: finish LIF, emit spikes + combined vec ----------
__global__ __launch_bounds__(256) void lif_finish(
    const float* __restrict__ partial, const float* __restrict__ potential,
    const float* __restrict__ prev_spk, float* __restrict__ out_spk,
    float* __restrict__ combined) {
    int j = blockIdx.x * 256 + threadIdx.x;
    float tc = 0.f;
    #pragma unroll
    for (int ic = 0; ic < 16; ++ic) tc += partial[ic * N + j];
    float p = potential[j];
    float v = p + (-p / TAU + tc);               // DT = 1
    float s = (v >= 1.0f) ? 1.f : 0.f;
    out_spk[j] = s;
    combined[j] = prev_spk[j];
    combined[N + j] = s;
}

// ---------------- Stage 2: h = relu(combined @ pW1^T + pb1) -----------------
__global__ __launch_bounds__(256) void mlp1(
    const float* __restrict__ combined, const float* __restrict__ pW1,
    const float* __restrict__ pb1, float* __restrict__ h) {
    __shared__ float red[256];
    int k = blockIdx.x;
    int t = threadIdx.x;
    const float* row = pW1 + (size_t)k * (2 * N);
    float acc = 0.f;
    #pragma unroll
    for (int u = 0; u < 8; ++u) {
        int j = t * 8 + u;
        acc = fmaf(combined[j], row[j], acc);
    }
    red[t] = acc;
    __syncthreads();
    for (int s = 128; s > 0; s >>= 1) {
        if (t < s) red[t] += red[t + s];
        __syncthreads();
    }
    if (t == 0) h[k] = fmaxf(red[0] + pb1[k], 0.f);
}

// ---------------- Stage 3: fused policy GEMV + sigmoid + plasticity ---------
// Each 16-lane group computes one W_rec element: dot(h, pW2[prune_row]) and
// dot(h, pW2[genesis_row]) via float4 loads; wave covers 4 consecutive
// elements -> two contiguous 1KiB global reads per iteration.
__global__ __launch_bounds__(256) void policy_update(
    const float* __restrict__ pW2, const float* __restrict__ pb2,
    const float* __restrict__ W_rec, const float* __restrict__ h,
    float* __restrict__ out_rec) {
    int lane = threadIdx.x & 63;
    int wave = threadIdx.x >> 6;
    int group = lane >> 4;
    int sub = lane & 15;
    int gw = blockIdx.x * 4 + wave;              // global wave id, 8192 total
    const int GW = 2048 * 4;
    float4 hv = ((const float4*)h)[sub];         // h[4*sub .. 4*sub+3]
    for (int eb = gw * 4; eb < NE; eb += GW * 4) {
        int e = eb + group;
        const float4* prow = (const float4*)(pW2 + (size_t)e * 64);
        const float4* grow = (const float4*)(pW2 + ((size_t)NE + e) * 64);
        float4 a = prow[sub];
        float4 b = grow[sub];
        float sp = a.x * hv.x + a.y * hv.y + a.z * hv.z + a.w * hv.w;
        float sg = b.x * hv.x + b.y * hv.y + b.z * hv.z + b.w * hv.w;
        #pragma unroll
        for (int off = 1; off < 16; off <<= 1) {
            sp += __shfl_xor(sp, off);
            sg += __shfl_xor(sg, off);
        }
        if (sub == 0) {
            float pol_p = sp + pb2[e];
            float pol_g = sg + pb2[NE + e];
            float sig_p = 1.f / (1.f + __expf(-pol_p));
            float sig_g = 1.f / (1.f + __expf(-pol_g));
            float w = W_rec[e];
            float nw = fmaxf(w - LR * sig_p + LR * sig_g, 0.f);
            int r = e >> 10, c = e & (N - 1);
            if (r == c) nw = 0.f;
            out_rec[e] = nw;
        }
    }
}

extern "C" void kernel_launch(void* const* d_in, const int* in_sizes, int n_in,
                              void* d_out, int out_size, void* d_ws, size_t ws_size,
                              hipStream_t stream) {
    const float* in_spk    = (const float*)d_in[0];
    const float* prev_spk  = (const float*)d_in[1];
    const float* potential = (const float*)d_in[2];
    const float* W_in      = (const float*)d_in[3];
    const float* W_rec     = (const float*)d_in[4];
    const float* pW1       = (const float*)d_in[5];
    const float* pb1       = (const float*)d_in[6];
    const float* pW2       = (const float*)d_in[7];
    const float* pb2       = (const float*)d_in[8];
    float* out = (float*)d_out;                  // [0,1024): spikes, then W_rec
    float* ws  = (float*)d_ws;
    float* partial  = ws;                        // 16*1024 floats
    float* combined = ws + 16 * N;               // 2048 floats
    float* h        = ws + 16 * N + 2 * N;       // 64 floats (16B-aligned)

    lif_partial<<<64, 256, 0, stream>>>(in_spk, prev_spk, W_in, W_rec, partial);
    lif_finish<<<4, 256, 0, stream>>>(partial, potential, prev_spk, out, combined);
    mlp1<<<64, 256, 0, stream>>>(combined, pW1, pb1, h);
    policy_update<<<2048, 256, 0, stream>>>(pW2, pb2, W_rec, h, out + N);
}

// Round 3
// 124.340 us; speedup vs baseline: 1.1253x; 1.1253x over previous
//
#include <hip/hip_runtime.h>

#define N 1024
#define NUM_IN 2048
#define NE (N * N)              // 1048576 elements of W_rec
#define TAU 20.0f
#define LR 0.001f
#define CHUNKS 64
#define RPC 48                  // rows per chunk: 64*48 = 3072 reduction rows

typedef float f4 __attribute__((ext_vector_type(4)));

// ---------------- Stage 1: partial sums of total_current --------------------
// 3072 logical rows (2048 W_in + 1024 W_rec) split into 64 chunks of 48 rows;
// 4 column groups -> 256 blocks (1/CU). Spikes staged in LDS so the per-row
// skip branch doesn't serialize the W-row loads.
__global__ __launch_bounds__(256) void lif_partial(
    const float* __restrict__ in_spk, const float* __restrict__ prev_spk,
    const float* __restrict__ W_in, const float* __restrict__ W_rec,
    float* __restrict__ partial) {
    __shared__ float spk[RPC];
    int jg = blockIdx.x & 3;
    int ic = blockIdx.x >> 2;
    int j = jg * 256 + threadIdx.x;
    int r0 = ic * RPC;
    if (threadIdx.x < RPC) {
        int r = r0 + threadIdx.x;
        spk[threadIdx.x] = (r < NUM_IN) ? in_spk[r] : prev_spk[r - NUM_IN];
    }
    __syncthreads();
    float acc = 0.f;
    #pragma unroll 4
    for (int u = 0; u < RPC; ++u) {
        int r = r0 + u;
        float s = spk[u];
        if (s != 0.f) {
            const float* Wrow = (r < NUM_IN) ? (W_in + (size_t)r * N)
                                             : (W_rec + (size_t)(r - NUM_IN) * N);
            acc = fmaf(s, Wrow[j], acc);
        }
    }
    partial[ic * N + j] = acc;
}

// ---------------- Stage 2: finish LIF + h = relu(combined @ pW1^T + pb1) ----
// 64 blocks; each block redundantly builds the full combined vector in LDS
// (partial buffer is L2-resident), block 0 writes spikes; block k computes h[k].
__global__ __launch_bounds__(256) void finish_mlp1(
    const float* __restrict__ partial, const float* __restrict__ potential,
    const float* __restrict__ prev_spk, const float* __restrict__ pW1,
    const float* __restrict__ pb1, float* __restrict__ out_spk,
    float* __restrict__ h) {
    __shared__ float comb[2 * N];
    __shared__ float red[256];
    int t = threadIdx.x;
    #pragma unroll
    for (int n0 = 0; n0 < N; n0 += 256) {
        int j = n0 + t;
        float tc = 0.f;
        #pragma unroll 8
        for (int ic = 0; ic < CHUNKS; ++ic) tc += partial[ic * N + j];
        float p = potential[j];
        float v = p + (-p / TAU + tc);           // DT = 1
        float s = (v >= 1.0f) ? 1.f : 0.f;
        comb[j] = prev_spk[j];
        comb[N + j] = s;
        if (blockIdx.x == 0) out_spk[j] = s;
    }
    __syncthreads();
    const float* row = pW1 + (size_t)blockIdx.x * (2 * N);
    float acc = 0.f;
    #pragma unroll
    for (int u = 0; u < 8; ++u) {
        int j = u * 256 + t;
        acc = fmaf(comb[j], row[j], acc);
    }
    red[t] = acc;
    __syncthreads();
    for (int s = 128; s > 0; s >>= 1) {
        if (t < s) red[t] += red[t + s];
        __syncthreads();
    }
    if (t == 0) h[blockIdx.x] = fmaxf(red[0] + pb1[blockIdx.x], 0.f);
}

// ---------------- Stage 3: fused policy GEMV + sigmoid + plasticity ---------
// 16 lanes per output element; wave covers 4 consecutive elements -> two
// contiguous 1KiB nontemporal reads per iteration. 8192 waves = exactly the
// resident capacity (32 waves/CU x 256 CU); 32 iterations each.
__global__ __launch_bounds__(256) void policy_update(
    const float* __restrict__ pW2, const float* __restrict__ pb2,
    const float* __restrict__ W_rec, const float* __restrict__ h,
    float* __restrict__ out_rec) {
    int lane = threadIdx.x & 63;
    int wave = threadIdx.x >> 6;
    int group = lane >> 4;
    int sub = lane & 15;
    int gw = blockIdx.x * 4 + wave;              // global wave id, 8192 total
    const int GW = 2048 * 4;
    f4 hv = ((const f4*)h)[sub];                 // h[4*sub .. 4*sub+3]
    #pragma unroll 2
    for (int eb = gw * 4; eb < NE; eb += GW * 4) {
        int e = eb + group;
        const f4* prow = (const f4*)(pW2 + (size_t)e * 64);
        const f4* grow = (const f4*)(pW2 + ((size_t)NE + e) * 64);
        f4 a = __builtin_nontemporal_load(prow + sub);
        f4 b = __builtin_nontemporal_load(grow + sub);
        float bp = 0.f, bg = 0.f, w = 0.f;
        if (sub == 0) {                          // issue before shuffle chain
            bp = pb2[e];
            bg = pb2[NE + e];
            w = W_rec[e];
        }
        float sp = a.x * hv.x + a.y * hv.y + a.z * hv.z + a.w * hv.w;
        float sg = b.x * hv.x + b.y * hv.y + b.z * hv.z + b.w * hv.w;
        #pragma unroll
        for (int off = 1; off < 16; off <<= 1) {
            sp += __shfl_xor(sp, off);
            sg += __shfl_xor(sg, off);
        }
        if (sub == 0) {
            float sig_p = 1.f / (1.f + __expf(-(sp + bp)));
            float sig_g = 1.f / (1.f + __expf(-(sg + bg)));
            float nw = fmaxf(w - LR * sig_p + LR * sig_g, 0.f);
            int r = e >> 10, c = e & (N - 1);
            if (r == c) nw = 0.f;
            out_rec[e] = nw;
        }
    }
}

extern "C" void kernel_launch(void* const* d_in, const int* in_sizes, int n_in,
                              void* d_out, int out_size, void* d_ws, size_t ws_size,
                              hipStream_t stream) {
    const float* in_spk    = (const float*)d_in[0];
    const float* prev_spk  = (const float*)d_in[1];
    const float* potential = (const float*)d_in[2];
    const float* W_in      = (const float*)d_in[3];
    const float* W_rec     = (const float*)d_in[4];
    const float* pW1       = (const float*)d_in[5];
    const float* pb1       = (const float*)d_in[6];
    const float* pW2       = (const float*)d_in[7];
    const float* pb2       = (const float*)d_in[8];
    float* out = (float*)d_out;                  // [0,1024): spikes, then W_rec
    float* ws  = (float*)d_ws;
    float* partial = ws;                         // 64*1024 floats
    float* h       = ws + CHUNKS * N;            // 64 floats (16B-aligned)

    lif_partial<<<256, 256, 0, stream>>>(in_spk, prev_spk, W_in, W_rec, partial);
    finish_mlp1<<<64, 256, 0, stream>>>(partial, potential, prev_spk, pW1, pb1, out, h);
    policy_update<<<2048, 256, 0, stream>>>(pW2, pb2, W_rec, h, out + N);
}

// Round 4
// 120.147 us; speedup vs baseline: 1.1646x; 1.0349x over previous
//
#include <hip/hip_runtime.h>

#define N 1024
#define NUM_IN 2048
#define NE (N * N)              // 1048576 elements of W_rec
#define TAU 20.0f
#define LR 0.001f
#define CHUNKS 64
#define RPC 48                  // rows per chunk: 64*48 = 3072 reduction rows

typedef float f4 __attribute__((ext_vector_type(4)));

// ---------------- Stage 1: partial sums of total_current --------------------
__global__ __launch_bounds__(256) void lif_partial(
    const float* __restrict__ in_spk, const float* __restrict__ prev_spk,
    const float* __restrict__ W_in, const float* __restrict__ W_rec,
    float* __restrict__ partial) {
    __shared__ float spk[RPC];
    int jg = blockIdx.x & 3;
    int ic = blockIdx.x >> 2;
    int j = jg * 256 + threadIdx.x;
    int r0 = ic * RPC;
    if (threadIdx.x < RPC) {
        int r = r0 + threadIdx.x;
        spk[threadIdx.x] = (r < NUM_IN) ? in_spk[r] : prev_spk[r - NUM_IN];
    }
    __syncthreads();
    float acc = 0.f;
    #pragma unroll 4
    for (int u = 0; u < RPC; ++u) {
        int r = r0 + u;
        float s = spk[u];
        if (s != 0.f) {
            const float* Wrow = (r < NUM_IN) ? (W_in + (size_t)r * N)
                                             : (W_rec + (size_t)(r - NUM_IN) * N);
            acc = fmaf(s, Wrow[j], acc);
        }
    }
    partial[ic * N + j] = acc;
}

// ---------------- Stage 2: finish LIF + h = relu(combined @ pW1^T + pb1) ----
__global__ __launch_bounds__(256) void finish_mlp1(
    const float* __restrict__ partial, const float* __restrict__ potential,
    const float* __restrict__ prev_spk, const float* __restrict__ pW1,
    const float* __restrict__ pb1, float* __restrict__ out_spk,
    float* __restrict__ h) {
    __shared__ float comb[2 * N];
    __shared__ float red[256];
    int t = threadIdx.x;
    #pragma unroll
    for (int n0 = 0; n0 < N; n0 += 256) {
        int j = n0 + t;
        float tc = 0.f;
        #pragma unroll 8
        for (int ic = 0; ic < CHUNKS; ++ic) tc += partial[ic * N + j];
        float p = potential[j];
        float v = p + (-p / TAU + tc);           // DT = 1
        float s = (v >= 1.0f) ? 1.f : 0.f;
        comb[j] = prev_spk[j];
        comb[N + j] = s;
        if (blockIdx.x == 0) out_spk[j] = s;
    }
    __syncthreads();
    const float* row = pW1 + (size_t)blockIdx.x * (2 * N);
    float acc = 0.f;
    #pragma unroll
    for (int u = 0; u < 8; ++u) {
        int j = u * 256 + t;
        acc = fmaf(comb[j], row[j], acc);
    }
    red[t] = acc;
    __syncthreads();
    for (int s = 128; s > 0; s >>= 1) {
        if (t < s) red[t] += red[t + s];
        __syncthreads();
    }
    if (t == 0) h[blockIdx.x] = fmaxf(red[0] + pb1[blockIdx.x], 0.f);
}

// ---------------- Stage 3: fused policy GEMV + sigmoid + plasticity ---------
// 16 lanes per output element; wave covers 4 consecutive elements -> two
// contiguous 1KiB nontemporal reads per iteration. Explicit 2-deep software
// pipeline: iteration it+1's loads are issued BEFORE iteration it's compute,
// so every wave keeps 2KB in flight during the shuffle/exp chain.
#define ITERS 32
#define ESTRIDE (8192 * 4)                       // elements advanced per iter
__global__ __launch_bounds__(256) void policy_update(
    const float* __restrict__ pW2, const float* __restrict__ pb2,
    const float* __restrict__ W_rec, const float* __restrict__ h,
    float* __restrict__ out_rec) {
    int lane = threadIdx.x & 63;
    int wave = threadIdx.x >> 6;
    int group = lane >> 4;
    int sub = lane & 15;
    int gw = blockIdx.x * 4 + wave;              // global wave id, 8192 total
    f4 hv = ((const f4*)h)[sub];                 // h[4*sub .. 4*sub+3]
    int e0 = gw * 4 + group;                     // this group's first element
    const f4* pr = (const f4*)(pW2 + (size_t)e0 * 64) + sub;
    const f4* gr = (const f4*)(pW2 + ((size_t)NE + e0) * 64) + sub;
    const size_t FSTRIDE = (size_t)ESTRIDE * 16; // f4 stride per iteration

    // prologue: load iteration 0
    f4 a = __builtin_nontemporal_load(pr);
    f4 b = __builtin_nontemporal_load(gr);
    float bp = 0.f, bg = 0.f, w = 0.f;
    if (sub == 0) { bp = pb2[e0]; bg = pb2[NE + e0]; w = W_rec[e0]; }

    for (int it = 0; it < ITERS; ++it) {
        // issue NEXT iteration's loads first (stay in flight during compute)
        f4 an{}, bn{};
        float bpn = 0.f, bgn = 0.f, wn = 0.f;
        if (it + 1 < ITERS) {
            const f4* prn = pr + (size_t)(it + 1) * FSTRIDE;
            const f4* grn = gr + (size_t)(it + 1) * FSTRIDE;
            an = __builtin_nontemporal_load(prn);
            bn = __builtin_nontemporal_load(grn);
            if (sub == 0) {
                int en = e0 + (it + 1) * ESTRIDE;
                bpn = pb2[en]; bgn = pb2[NE + en]; wn = W_rec[en];
            }
        }
        // compute current iteration
        float sp = a.x * hv.x + a.y * hv.y + a.z * hv.z + a.w * hv.w;
        float sg = b.x * hv.x + b.y * hv.y + b.z * hv.z + b.w * hv.w;
        #pragma unroll
        for (int off = 1; off < 16; off <<= 1) {
            sp += __shfl_xor(sp, off);
            sg += __shfl_xor(sg, off);
        }
        if (sub == 0) {
            int e = e0 + it * ESTRIDE;
            float sig_p = 1.f / (1.f + __expf(-(sp + bp)));
            float sig_g = 1.f / (1.f + __expf(-(sg + bg)));
            float nw = fmaxf(w - LR * sig_p + LR * sig_g, 0.f);
            int r = e >> 10, c = e & (N - 1);
            if (r == c) nw = 0.f;
            out_rec[e] = nw;
        }
        a = an; b = bn; bp = bpn; bg = bgn; w = wn;
    }
}

extern "C" void kernel_launch(void* const* d_in, const int* in_sizes, int n_in,
                              void* d_out, int out_size, void* d_ws, size_t ws_size,
                              hipStream_t stream) {
    const float* in_spk    = (const float*)d_in[0];
    const float* prev_spk  = (const float*)d_in[1];
    const float* potential = (const float*)d_in[2];
    const float* W_in      = (const float*)d_in[3];
    const float* W_rec     = (const float*)d_in[4];
    const float* pW1       = (const float*)d_in[5];
    const float* pb1       = (const float*)d_in[6];
    const float* pW2       = (const float*)d_in[7];
    const float* pb2       = (const float*)d_in[8];
    float* out = (float*)d_out;                  // [0,1024): spikes, then W_rec
    float* ws  = (float*)d_ws;
    float* partial = ws;                         // 64*1024 floats
    float* h       = ws + CHUNKS * N;            // 64 floats (16B-aligned)

    lif_partial<<<256, 256, 0, stream>>>(in_spk, prev_spk, W_in, W_rec, partial);
    finish_mlp1<<<64, 256, 0, stream>>>(partial, potential, prev_spk, pW1, pb1, out, h);
    policy_update<<<2048, 256, 0, stream>>>(pW2, pb2, W_rec, h, out + N);
}